// Round 4
// baseline (69846.765 us; speedup 1.0000x reference)
//
#include <hip/hip_runtime.h>

// Seq2Seq LSTM H=128: enc 8192 + dec 4096 strictly sequential steps.
// Single block, one CU, 512 threads (8 waves). ONE barrier per step.
//
// Model (R11, @1.63GHz sustained): 1071 cyc/step/SIMD; FMA-issue floor
// 256 (512 pk_fma/step, 2 waves/SIMD); ~64% VALU-busy on the active CU
// => issue-bound + ~300 cyc barrier/latency.
//
// R12 changes:
//  * Branchless gate nonlinearity: v = fma(B, rcp(1+exp(S*a)), A) with
//    per-lane (A,B,S) = g==2 ? (1,-2,2) : (0,1,-1). Bit-identical to
//    the old tanhfast/sigm per lane, but ONE exp+rcp and no divergent
//    dual execution (old ?: issued both paths under exec mask).
//  * Partial exchange via LDS float atomics: writers do 8x no-rtn
//    ds_add_f32 into part[pb][5*lane+SOFF[s]] (banks 2-way; adds run
//    in the LDS pipe under MATVEC issue). Reader: ONE ds_read_b32 at
//    prd (no 8-slot gather, no 7-add tree), then re-zeroes its slot
//    for reuse 2 steps later (safe: barrier+lgkmcnt drain separates
//    reader-zero from the next ds_adds of that parity).
//    Accumulation order becomes timing-dependent; R11 showed outputs
//    are robust to reassociation (absmax stayed 0.0).

#define H      128
#define ENC_T  8192
#define DEC_T  4096
#define NT     512
#define NBLK   1
#define PBUF   640          // floats per partial buffer: prd <= 638

typedef float v2f __attribute__((ext_vector_type(2)));

__device__ __forceinline__ v2f pk_fma_s(v2f a, v2f b_sgpr, v2f c) {
    v2f d;   // b is wave-uniform: read as 64-bit scalar operand (s-pair)
    asm("v_pk_fma_f32 %0, %1, %2, %3" : "=v"(d) : "v"(a), "s"(b_sgpr), "v"(c));
    return d;
}
__device__ __forceinline__ v2f pk_fma(v2f a, v2f b, v2f c) {
    v2f d;
    asm("v_pk_fma_f32 %0, %1, %2, %3" : "=v"(d) : "v"(a), "v"(b), "v"(c));
    return d;
}
__device__ __forceinline__ float tanhfast(float x) {
    return 1.0f - 2.0f * __builtin_amdgcn_rcpf(1.0f + __expf(2.0f * x));
}
__device__ __forceinline__ float rdlane(float v, int l) {
    return __int_as_float(__builtin_amdgcn_readlane(__float_as_int(v), l));
}
template <int CTRL>
__device__ __forceinline__ float qperm(float v) {      // DPP quad_perm, VALU-speed
    return __int_as_float(
        __builtin_amdgcn_mov_dpp(__float_as_int(v), CTRL, 0xf, 0xf, true));
}

__global__ __launch_bounds__(NT, 2)
void seq2seq_lstm(const float* __restrict__ input_seq,
                  const float* __restrict__ enc_Wih,
                  const float* __restrict__ enc_Whh,
                  const float* __restrict__ enc_bih,
                  const float* __restrict__ enc_bhh,
                  const float* __restrict__ dec_Wih,
                  const float* __restrict__ dec_Whh,
                  const float* __restrict__ dec_bih,
                  const float* __restrict__ dec_bhh,
                  const float* __restrict__ fc_W,
                  const float* __restrict__ fc_b,
                  float* __restrict__ out,
                  unsigned* __restrict__ wsflag)
{
    (void)wsflag;
    __shared__ __align__(16) float xin[ENC_T];          // 32 KB
    __shared__ __align__(16) float hbuf[2][H];          // h history (off-path)
    __shared__ __align__(16) float part[2][PBUF];       // dbl-buffered row sums

    const int t    = threadIdx.x;      // 0..511
    const int lane = t & 63;
    const int wv   = t >> 6;           // wave 0..7, j-slice [16wv,16wv+16)
    const int jb   = 16 * wv;
    const int qq   = lane >> 2;        // reduce role: unit-in-slice 0..15
    const int g    = lane & 3;         // gate 0=i 1=f 2=g 3=o
    const int myu  = jb + qq;          // my unit (global)
    const int myrow = g * H + myu;     // my gate row
    const int prd  = 5 * myu + g;      // my row-sum slot
    const int pw5  = 5 * lane;         // writer base; +SOFF folds into ds imm

    // branchless nonlin constants: g==2 -> tanh-form, else sigmoid-form
    const float sA = (g == 2) ? 1.0f : 0.0f;
    const float sB = (g == 2) ? -2.0f : 1.0f;
    const float sS = (g == 2) ? 2.0f : -1.0f;

    {   // zero partial accumulators (both parities) before first use
        float* p0 = (float*)part;
        for (int i = t; i < 2 * PBUF; i += NT) p0[i] = 0.f;
    }
    {   // stage input sequence
        const float4* s = (const float4*)input_seq;
        float4* d = (float4*)xin;
        for (int i = t; i < ENC_T / 4; i += NT) d[i] = s[i];
    }

    // matvec weights as j-pairs: w2[s][jj] = Whh[(64s+lane)][jb+2jj, jb+2jj+1]
    v2f w2[8][8];
#pragma unroll
    for (int s = 0; s < 8; ++s) {
        const v2f* Wr = (const v2f*)(enc_Whh + (64 * s + lane) * H + jb);
#pragma unroll
        for (int jj = 0; jj < 8; ++jj) w2[s][jj] = Wr[jj];
    }
    float bias_r = enc_bih[myrow] + enc_bhh[myrow];
    float wih_r  = enc_Wih[myrow];

    float cst = 0.f;      // cell state of unit myu (replicated per quad)
    float hn  = 0.f;      // h of unit myu (replicated per quad)
    __syncthreads();

    // h[jb+2jj+c] lives in quad 2jj+c of this wave -> g==3 lane 8jj+4c+3
    // row 64s+lane -> slot pw5 + SOFF[s], SOFF = 320(s&1) + (s>>1)
#define MATVEC(PB)                                                          \
    {                                                                       \
        v2f acc2[8];                                                        \
        _Pragma("unroll") for (int s = 0; s < 8; ++s)                       \
            acc2[s] = (v2f){0.f, 0.f};                                      \
        _Pragma("unroll") for (int jj = 0; jj < 8; ++jj) {                  \
            const float se = rdlane(hn, 8 * jj + 3);                        \
            const float so = rdlane(hn, 8 * jj + 7);                        \
            const v2f hp = {se, so};                                        \
            _Pragma("unroll") for (int s = 0; s < 8; ++s)                   \
                acc2[s] = pk_fma_s(w2[s][jj], hp, acc2[s]);                 \
        }                                                                   \
        float* pb_ = &part[PB][pw5];                                        \
        atomicAdd(pb_ + 0,   acc2[0].x + acc2[0].y);                        \
        atomicAdd(pb_ + 320, acc2[1].x + acc2[1].y);                        \
        atomicAdd(pb_ + 1,   acc2[2].x + acc2[2].y);                        \
        atomicAdd(pb_ + 321, acc2[3].x + acc2[3].y);                        \
        atomicAdd(pb_ + 2,   acc2[4].x + acc2[4].y);                        \
        atomicAdd(pb_ + 322, acc2[5].x + acc2[5].y);                        \
        atomicAdd(pb_ + 3,   acc2[6].x + acc2[6].y);                        \
        atomicAdd(pb_ + 323, acc2[7].x + acc2[7].y);                        \
    }

    // read my row sum, then re-zero the slot for reuse 2 steps later
#define RED_LOAD(PB)                                                        \
    const float a8_ = part[PB][prd];                                        \
    part[PB][prd] = 0.f;

    // STH: 1 -> store h to hbuf[PB] (decoder out reads stale hbuf)
#define RED_FIN(PB, ABASE, STH)                                             \
    {                                                                       \
        const float a = (ABASE) + a8_;                                      \
        const float e = __expf(sS * a);                                     \
        const float r = __builtin_amdgcn_rcpf(1.0f + e);                    \
        const float v = fmaf(sB, r, sA);                                    \
        const float vi = qperm<0x00>(v);   /* quad lane 0 */                \
        const float vf = qperm<0x55>(v);   /* quad lane 1 */                \
        const float vg = qperm<0xAA>(v);   /* quad lane 2 */                \
        const float vo = qperm<0xFF>(v);   /* quad lane 3 */                \
        cst = fmaf(vf, cst, vi * vg);                                       \
        hn  = vo * tanhfast(cst);                                           \
        if (STH && g == 3) hbuf[PB][myu] = hn;                              \
    }

    // post-barrier fc output: out[ST-1] from hbuf[HB] (= h after step ST-1;
    // stable: this step's REDUCE writes hbuf[1-HB]). Runs in wave 7's
    // part-read latency shadow.
#define OUTBLK(ST, HB)                                                      \
    if (wv == 7 && (ST) >= 1) {                                             \
        float p = fmaf(fwl, hbuf[HB][lane], fwh * hbuf[HB][64 + lane]);     \
        p += qperm<0xB1>(p);               /* xor 1 */                      \
        p += qperm<0x4E>(p);               /* xor 2 */                      \
        _Pragma("unroll") for (int m = 32; m >= 4; m >>= 1)                 \
            p += __shfl_xor(p, m, 64);                                      \
        if (lane == 0) out[(ST) - 1] = p + fcb;                             \
    }

    // ---------------- encoder: 8192 steps, ONE barrier each ----------------
    for (int st = 0; st < ENC_T; st += 2) {
        {
            MATVEC(0);
            const float x = xin[st];
            __syncthreads();
            RED_LOAD(0);
            RED_FIN(0, fmaf(wih_r, x, bias_r), 0);
        }
        {
            MATVEC(1);
            const float x = xin[st + 1];
            __syncthreads();
            RED_LOAD(1);
            RED_FIN(1, fmaf(wih_r, x, bias_r), 0);
        }
    }
    if (g == 3) hbuf[1][myu] = hn;         // final encoder h, once

    // ---------------- decoder setup: fold fc into Whh ----------------
    const float fcb = fc_b[0];
    const float fwl = fc_W[lane];
    const float fwh = fc_W[64 + lane];
#pragma unroll
    for (int s = 0; s < 8; ++s) {
        const int r = 64 * s + lane;
        const float vi = dec_Wih[r];
        const v2f vip = {vi, vi};
        const v2f* Wr = (const v2f*)(dec_Whh + r * H + jb);
        const v2f* Fr = (const v2f*)(fc_W + jb);
#pragma unroll
        for (int jj = 0; jj < 8; ++jj)
            w2[s][jj] = pk_fma(vip, Fr[jj], Wr[jj]);   // W' = Whh + wih (x) fcW
    }
    wih_r  = dec_Wih[myrow];
    bias_r = dec_bih[myrow] + dec_bhh[myrow] + wih_r * fcb;
    __syncthreads();                       // h_enc visible in hbuf[1]
    float q0;
    {
        float p = fmaf(fwl, hbuf[1][lane], fwh * hbuf[1][64 + lane]);
        p += qperm<0xB1>(p);               // xor 1
        p += qperm<0x4E>(p);               // xor 2
#pragma unroll
        for (int m = 32; m >= 4; m >>= 1) p += __shfl_xor(p, m, 64);
        q0 = p + fcb;
    }
    float cb = bias_r - wih_r * q0;        // step-0 correction (y0 = 0)

    // ---------------- decoder: 4096 steps ----------------
    for (int st = 0; st < DEC_T; st += 2) {
        {   // even step ST=st: out[st-1] from hbuf[1] (odd-parity h)
            MATVEC(0);
            __syncthreads();
            RED_LOAD(0);
            OUTBLK(st, 1);
            RED_FIN(0, cb, 1);
            cb = bias_r;
        }
        {   // odd step ST=st+1: out[st] from hbuf[0]
            MATVEC(1);
            __syncthreads();
            RED_LOAD(1);
            OUTBLK(st + 1, 0);
            RED_FIN(1, cb, 1);
        }
    }

    // tail: out[DEC_T-1] from hbuf[1] (h after final step, parity 1)
    __syncthreads();
    if (wv == 7) {
        float p = fmaf(fwl, hbuf[1][lane], fwh * hbuf[1][64 + lane]);
        p += qperm<0xB1>(p);
        p += qperm<0x4E>(p);
#pragma unroll
        for (int m = 32; m >= 4; m >>= 1) p += __shfl_xor(p, m, 64);
        if (lane == 0) out[DEC_T - 1] = p + fcb;
    }
}

extern "C" void kernel_launch(void* const* d_in, const int* in_sizes, int n_in,
                              void* d_out, int out_size, void* d_ws, size_t ws_size,
                              hipStream_t stream)
{
    (void)in_sizes; (void)n_in; (void)ws_size; (void)out_size;
    seq2seq_lstm<<<NBLK, NT, 0, stream>>>(
        (const float*)d_in[0],   // input_seq
        (const float*)d_in[1],   // enc_Wih
        (const float*)d_in[2],   // enc_Whh
        (const float*)d_in[3],   // enc_bih
        (const float*)d_in[4],   // enc_bhh
        (const float*)d_in[5],   // dec_Wih
        (const float*)d_in[6],   // dec_Whh
        (const float*)d_in[7],   // dec_bih
        (const float*)d_in[8],   // dec_bhh
        (const float*)d_in[9],   // fc_W
        (const float*)d_in[10],  // fc_b
        (float*)d_out,
        (unsigned*)d_ws);
}

// Round 5
// 7808.062 us; speedup vs baseline: 8.9455x; 8.9455x over previous
//
#include <hip/hip_runtime.h>

// Seq2Seq LSTM H=128: enc 8192 + dec 4096 strictly sequential steps.
// Single block, one CU, 512 threads (8 waves). ONE barrier per step.
//
// R13. R12 POST-MORTEM: shared-float atomicAdd lowered to a CAS retry
// loop (not ds_add_f32) -> 12x regression under 8-way slot contention.
// Exchange REVERTED to R11's verified scheme: writer 8x scattered b32
// (flat = 8*pw + (wv ^ ((pw>>2)&7))), reader 2x ds_read_b128 + 7-add
// tree. R11 measured 8073 us steady (=1071 cyc/step @1.63GHz, ~64%
// active-CU VALU busy => issue-bound).
//
// R13 changes vs R11 (pure issue-count cuts, bit-identical math):
//  * acc-init eliminated: first jj-iter uses v_pk_mul_f32 (16 fewer
//    v_mov per lane per step).
//  * Branchless gate nonlinearity: v = fma(B, rcp(1+exp(S*a)), A),
//    (A,B,S) = g==2 ? (1,-2,2) : (0,1,-1). One exp+rcp, no divergent
//    dual-path execution. Bit-identical per lane to sigm/tanhfast.
//  * Encoder x loaded as float2 pair per 2-step unroll.
// Predicted: ~985 cyc/step -> ~7.4-7.7 ms steady.

#define H      128
#define ENC_T  8192
#define DEC_T  4096
#define NT     512
#define NBLK   1
#define PBUF   5120         // floats per partial buffer: 8*638+7 < 5120

typedef float v2f __attribute__((ext_vector_type(2)));

__device__ __forceinline__ v2f pk_fma_s(v2f a, v2f b_sgpr, v2f c) {
    v2f d;   // b is wave-uniform: read as 64-bit scalar operand (s-pair)
    asm("v_pk_fma_f32 %0, %1, %2, %3" : "=v"(d) : "v"(a), "s"(b_sgpr), "v"(c));
    return d;
}
__device__ __forceinline__ v2f pk_mul_s(v2f a, v2f b_sgpr) {
    v2f d;   // first-iteration accumulator: acc = w*h (no zero-init)
    asm("v_pk_mul_f32 %0, %1, %2" : "=v"(d) : "v"(a), "s"(b_sgpr));
    return d;
}
__device__ __forceinline__ v2f pk_fma(v2f a, v2f b, v2f c) {
    v2f d;
    asm("v_pk_fma_f32 %0, %1, %2, %3" : "=v"(d) : "v"(a), "v"(b), "v"(c));
    return d;
}
__device__ __forceinline__ float tanhfast(float x) {
    return 1.0f - 2.0f * __builtin_amdgcn_rcpf(1.0f + __expf(2.0f * x));
}
__device__ __forceinline__ float rdlane(float v, int l) {
    return __int_as_float(__builtin_amdgcn_readlane(__float_as_int(v), l));
}
template <int CTRL>
__device__ __forceinline__ float qperm(float v) {      // DPP quad_perm, VALU-speed
    return __int_as_float(
        __builtin_amdgcn_mov_dpp(__float_as_int(v), CTRL, 0xf, 0xf, true));
}

__global__ __launch_bounds__(NT, 2)
void seq2seq_lstm(const float* __restrict__ input_seq,
                  const float* __restrict__ enc_Wih,
                  const float* __restrict__ enc_Whh,
                  const float* __restrict__ enc_bih,
                  const float* __restrict__ enc_bhh,
                  const float* __restrict__ dec_Wih,
                  const float* __restrict__ dec_Whh,
                  const float* __restrict__ dec_bih,
                  const float* __restrict__ dec_bhh,
                  const float* __restrict__ fc_W,
                  const float* __restrict__ fc_b,
                  float* __restrict__ out,
                  unsigned* __restrict__ wsflag)
{
    (void)wsflag;
    __shared__ __align__(16) float xin[ENC_T];          // 32 KB
    __shared__ __align__(16) float hbuf[2][H];          // h history (off-path)
    __shared__ __align__(16) float part[2][PBUF];       // dbl-buffered partials

    const int t    = threadIdx.x;      // 0..511
    const int lane = t & 63;
    const int wv   = t >> 6;           // wave 0..7, j-slice [16wv,16wv+16)
    const int jb   = 16 * wv;
    const int qq   = lane >> 2;        // reduce role: unit-in-slice 0..15
    const int g    = lane & 3;         // gate 0=i 1=f 2=g 3=o
    const int myu  = jb + qq;          // my unit (global)
    const int myrow = g * H + myu;     // my gate row

    // reader addresses: row's 8 partials contiguous at 8*prd
    const int prd = 5 * myu + g;
    const int pA  = (prd >> 2) & 1;                 // half-order spread
    const int rA  = 8 * prd + 4 * pA;
    const int rB  = 8 * prd + 4 - 4 * pA;
    // writer addresses: value for row 64s+lane -> block 8*pw, col wv^swz
    int widx[8];
    {
        const int SOFF[8] = {0, 320, 1, 321, 2, 322, 3, 323};
#pragma unroll
        for (int s = 0; s < 8; ++s) {
            const int pw = 5 * lane + SOFF[s];
            widx[s] = 8 * pw + (wv ^ ((pw >> 2) & 7));
        }
    }

    // branchless nonlin constants: g==2 -> tanh-form, else sigmoid-form
    const float sA = (g == 2) ? 1.0f : 0.0f;
    const float sB = (g == 2) ? -2.0f : 1.0f;
    const float sS = (g == 2) ? 2.0f : -1.0f;

    {   // stage input sequence
        const float4* s = (const float4*)input_seq;
        float4* d = (float4*)xin;
        for (int i = t; i < ENC_T / 4; i += NT) d[i] = s[i];
    }

    // matvec weights as j-pairs: w2[s][jj] = Whh[(64s+lane)][jb+2jj, jb+2jj+1]
    v2f w2[8][8];
#pragma unroll
    for (int s = 0; s < 8; ++s) {
        const v2f* Wr = (const v2f*)(enc_Whh + (64 * s + lane) * H + jb);
#pragma unroll
        for (int jj = 0; jj < 8; ++jj) w2[s][jj] = Wr[jj];
    }
    float bias_r = enc_bih[myrow] + enc_bhh[myrow];
    float wih_r  = enc_Wih[myrow];

    float cst = 0.f;      // cell state of unit myu (replicated per quad)
    float hn  = 0.f;      // h of unit myu (replicated per quad)
    __syncthreads();

    // h[jb+2jj+c] lives in quad 2jj+c of this wave -> g==3 lane 8jj+4c+3
#define MATVEC(PB)                                                          \
    {                                                                       \
        v2f acc2[8];                                                        \
        {   /* jj = 0: pk_mul, no accumulator init */                       \
            const float se = rdlane(hn, 3);                                 \
            const float so = rdlane(hn, 7);                                 \
            const v2f hp = {se, so};                                        \
            _Pragma("unroll") for (int s = 0; s < 8; ++s)                   \
                acc2[s] = pk_mul_s(w2[s][0], hp);                           \
        }                                                                   \
        _Pragma("unroll") for (int jj = 1; jj < 8; ++jj) {                  \
            const float se = rdlane(hn, 8 * jj + 3);                        \
            const float so = rdlane(hn, 8 * jj + 7);                        \
            const v2f hp = {se, so};                                        \
            _Pragma("unroll") for (int s = 0; s < 8; ++s)                   \
                acc2[s] = pk_fma_s(w2[s][jj], hp, acc2[s]);                 \
        }                                                                   \
        float* pb_ = &part[PB][0];                                          \
        _Pragma("unroll") for (int s = 0; s < 8; ++s)                       \
            pb_[widx[s]] = acc2[s].x + acc2[s].y;                           \
    }

#define RED_LOAD(PB)                                                        \
    const float4 a4_ = *(const float4*)&part[PB][rA];                       \
    const float4 b4_ = *(const float4*)&part[PB][rB];

    // STH: 1 -> store h to hbuf[PB] (decoder out reads stale hbuf)
#define RED_FIN(PB, ABASE, STH)                                             \
    {                                                                       \
        const float a = (ABASE) +                                           \
            (((a4_.x + a4_.y) + (a4_.z + a4_.w)) +                          \
             ((b4_.x + b4_.y) + (b4_.z + b4_.w)));                          \
        const float e = __expf(sS * a);                                     \
        const float r = __builtin_amdgcn_rcpf(1.0f + e);                    \
        const float v = fmaf(sB, r, sA);                                    \
        const float vi = qperm<0x00>(v);   /* quad lane 0 */                \
        const float vf = qperm<0x55>(v);   /* quad lane 1 */                \
        const float vg = qperm<0xAA>(v);   /* quad lane 2 */                \
        const float vo = qperm<0xFF>(v);   /* quad lane 3 */                \
        cst = fmaf(vf, cst, vi * vg);                                       \
        hn  = vo * tanhfast(cst);                                           \
        if (STH && g == 3) hbuf[PB][myu] = hn;                              \
    }

    // post-barrier fc output: out[ST-1] from hbuf[HB] (= h after step ST-1;
    // stable: this step's REDUCE writes hbuf[1-HB]). Runs in wave 7's
    // part-read latency shadow.
#define OUTBLK(ST, HB)                                                      \
    if (wv == 7 && (ST) >= 1) {                                             \
        float p = fmaf(fwl, hbuf[HB][lane], fwh * hbuf[HB][64 + lane]);     \
        p += qperm<0xB1>(p);               /* xor 1 */                      \
        p += qperm<0x4E>(p);               /* xor 2 */                      \
        _Pragma("unroll") for (int m = 32; m >= 4; m >>= 1)                 \
            p += __shfl_xor(p, m, 64);                                      \
        if (lane == 0) out[(ST) - 1] = p + fcb;                             \
    }

    // ---------------- encoder: 8192 steps, ONE barrier each ----------------
    for (int st = 0; st < ENC_T; st += 2) {
        const float2 xx = *(const float2*)&xin[st];
        {
            MATVEC(0);
            __syncthreads();
            RED_LOAD(0);
            RED_FIN(0, fmaf(wih_r, xx.x, bias_r), 0);
        }
        {
            MATVEC(1);
            __syncthreads();
            RED_LOAD(1);
            RED_FIN(1, fmaf(wih_r, xx.y, bias_r), 0);
        }
    }
    if (g == 3) hbuf[1][myu] = hn;         // final encoder h, once

    // ---------------- decoder setup: fold fc into Whh ----------------
    const float fcb = fc_b[0];
    const float fwl = fc_W[lane];
    const float fwh = fc_W[64 + lane];
#pragma unroll
    for (int s = 0; s < 8; ++s) {
        const int r = 64 * s + lane;
        const float vi = dec_Wih[r];
        const v2f vip = {vi, vi};
        const v2f* Wr = (const v2f*)(dec_Whh + r * H + jb);
        const v2f* Fr = (const v2f*)(fc_W + jb);
#pragma unroll
        for (int jj = 0; jj < 8; ++jj)
            w2[s][jj] = pk_fma(vip, Fr[jj], Wr[jj]);   // W' = Whh + wih (x) fcW
    }
    wih_r  = dec_Wih[myrow];
    bias_r = dec_bih[myrow] + dec_bhh[myrow] + wih_r * fcb;
    __syncthreads();                       // h_enc visible in hbuf[1]
    float q0;
    {
        float p = fmaf(fwl, hbuf[1][lane], fwh * hbuf[1][64 + lane]);
        p += qperm<0xB1>(p);               // xor 1
        p += qperm<0x4E>(p);               // xor 2
#pragma unroll
        for (int m = 32; m >= 4; m >>= 1) p += __shfl_xor(p, m, 64);
        q0 = p + fcb;
    }
    float cb = bias_r - wih_r * q0;        // step-0 correction (y0 = 0)

    // ---------------- decoder: 4096 steps ----------------
    for (int st = 0; st < DEC_T; st += 2) {
        {   // even step ST=st: out[st-1] from hbuf[1] (odd-parity h)
            MATVEC(0);
            __syncthreads();
            RED_LOAD(0);
            OUTBLK(st, 1);
            RED_FIN(0, cb, 1);
            cb = bias_r;
        }
        {   // odd step ST=st+1: out[st] from hbuf[0]
            MATVEC(1);
            __syncthreads();
            RED_LOAD(1);
            OUTBLK(st + 1, 0);
            RED_FIN(1, cb, 1);
        }
    }

    // tail: out[DEC_T-1] from hbuf[1] (h after final step, parity 1)
    __syncthreads();
    if (wv == 7) {
        float p = fmaf(fwl, hbuf[1][lane], fwh * hbuf[1][64 + lane]);
        p += qperm<0xB1>(p);
        p += qperm<0x4E>(p);
#pragma unroll
        for (int m = 32; m >= 4; m >>= 1) p += __shfl_xor(p, m, 64);
        if (lane == 0) out[DEC_T - 1] = p + fcb;
    }
}

extern "C" void kernel_launch(void* const* d_in, const int* in_sizes, int n_in,
                              void* d_out, int out_size, void* d_ws, size_t ws_size,
                              hipStream_t stream)
{
    (void)in_sizes; (void)n_in; (void)ws_size; (void)out_size;
    seq2seq_lstm<<<NBLK, NT, 0, stream>>>(
        (const float*)d_in[0],   // input_seq
        (const float*)d_in[1],   // enc_Wih
        (const float*)d_in[2],   // enc_Whh
        (const float*)d_in[3],   // enc_bih
        (const float*)d_in[4],   // enc_bhh
        (const float*)d_in[5],   // dec_Wih
        (const float*)d_in[6],   // dec_Whh
        (const float*)d_in[7],   // dec_bih
        (const float*)d_in[8],   // dec_bhh
        (const float*)d_in[9],   // fc_W
        (const float*)d_in[10],  // fc_b
        (float*)d_out,
        (unsigned*)d_ws);
}